// Round 3
// baseline (181.685 us; speedup 1.0000x reference)
//
#include <hip/hip_runtime.h>
#include <hip/hip_bf16.h>
#include <stdint.h>

#define NROWS 4096
#define DIMS  2048
#define BM    256
#define BK    64
#define NTILES (DIMS / BK)   // 32
#define NTB   (NROWS / BM)   // 16 tile-blocks per dim -> 256 blocks
#define MARGIN_F 0.3f

typedef __attribute__((ext_vector_type(8))) short bf16x8;
typedef __attribute__((ext_vector_type(4))) float f32x4;
typedef __attribute__((ext_vector_type(4))) unsigned short us4;

__device__ inline unsigned short f2bf(float x) {
  union { float f; unsigned int u; } c; c.f = x;
  unsigned int lsb = (c.u >> 16) & 1u;
  c.u += 0x7fffu + lsb;               // round-to-nearest-even
  return (unsigned short)(c.u >> 16);
}

__device__ inline void atomicMaxF(float* addr, float v) {
  if (v >= 0.f) atomicMax((int*)addr, __float_as_int(v));
  else          atomicMin((unsigned int*)addr, __float_as_uint(v));
}
__device__ inline void atomicMinF(float* addr, float v) {
  if (v >= 0.f) atomicMin((int*)addr, __float_as_int(v));
  else          atomicMax((unsigned int*)addr, __float_as_uint(v));
}

__device__ inline void load_lds16(const void* g, void* l) {
  __builtin_amdgcn_global_load_lds(
      (const __attribute__((address_space(1))) void*)(g),
      (__attribute__((address_space(3))) void*)(l), 16, 0, 0);
}

// ---------------- normalize rows to bf16 + init dap/dan ----------------
__global__ __launch_bounds__(256) void norm_kernel(const float* __restrict__ in,
                                                   short* __restrict__ l2,
                                                   float* __restrict__ dap,
                                                   float* __restrict__ dan) {
  int row = blockIdx.x;
  int t = threadIdx.x;
  const float4* rin = (const float4*)(in + (size_t)row * DIMS);
  float4 v0 = rin[t];
  float4 v1 = rin[t + 256];
  float ss = v0.x*v0.x + v0.y*v0.y + v0.z*v0.z + v0.w*v0.w
           + v1.x*v1.x + v1.y*v1.y + v1.z*v1.z + v1.w*v1.w;
  #pragma unroll
  for (int s = 1; s < 64; s <<= 1) ss += __shfl_xor(ss, s);
  __shared__ float wsum[4];
  if ((t & 63) == 0) wsum[t >> 6] = ss;
  __syncthreads();
  float tot = wsum[0] + wsum[1] + wsum[2] + wsum[3];
  float rn = 1.0f / sqrtf(tot);
  short* orow = l2 + (size_t)row * DIMS;
  us4 o0, o1;
  o0.x = f2bf(v0.x * rn); o0.y = f2bf(v0.y * rn);
  o0.z = f2bf(v0.z * rn); o0.w = f2bf(v0.w * rn);
  o1.x = f2bf(v1.x * rn); o1.y = f2bf(v1.y * rn);
  o1.z = f2bf(v1.z * rn); o1.w = f2bf(v1.w * rn);
  *(us4*)(orow + 4 * t) = o0;
  *(us4*)(orow + 4 * t + 1024) = o1;
  if (t == 0) { dap[row] = -__builtin_inff(); dan[row] = __builtin_inff(); }
}

// ---------------- fused GEMM (G = L . L^T) + masked row max/min ----------------
// 256x256 tile, 8 waves (2M x 4N; each wave owns 128x64), BK=64,
// 16x16x32 bf16 MFMA, double-buffered 128 KB LDS.
// Counted vmcnt(8) + raw s_barrier: next tile's 8 global_load_lds stay in
// flight across the full compute phase (T3+T4); 64 MFMA/wave per barrier pair.
// LDS chunk-major: chunk c = kgrp*256 + row holds L[row][kt*64 + kgrp*8 ..+8];
// staging is linear (lane*16B), fragment ds_read_b128 is conflict-free (2-way).
__global__ __launch_bounds__(512, 2) void gemm_reduce_kernel(
    const short* __restrict__ l2, const int* __restrict__ tgt,
    float* __restrict__ dap, float* __restrict__ dan) {
  __shared__ __attribute__((aligned(16))) short ldsA[2][16384];  // 2 x 32 KB
  __shared__ __attribute__((aligned(16))) short ldsB[2][16384];  // 2 x 32 KB

  // XCD-chunked bijective swizzle (256 blocks, 8 XCDs -> 32 contiguous per XCD)
  int c = blockIdx.x;
  int swz = (c & 7) * 32 + (c >> 3);
  int bi = swz >> 4, bj = swz & 15;

  int tid = threadIdx.x;
  int lane = tid & 63, w = tid >> 6;
  int wr = w >> 2;        // 0..1  (M half)
  int nc = w & 3;         // 0..3  (N quarter)

  f32x4 acc[8][4];
  #pragma unroll
  for (int m = 0; m < 8; m++)
    #pragma unroll
    for (int n = 0; n < 4; n++) acc[m][n] = (f32x4){0.f, 0.f, 0.f, 0.f};

  // per-thread staging source base: row = tid&255, k-base = (tid>>8)*8
  const short* gA = l2 + ((size_t)(bi * BM + (tid & 255))) * DIMS + (tid >> 8) * 8;
  const short* gB = l2 + ((size_t)(bj * BM + (tid & 255))) * DIMS + (tid >> 8) * 8;

  // fragment read indices (chunk units)
  int kofA = (lane >> 4) * 256 + wr * 128 + (lane & 15);
  int kofB = (lane >> 4) * 256 + nc * 64 + (lane & 15);

  #define STAGE(T, P)                                                         \
    do {                                                                      \
      _Pragma("unroll")                                                       \
      for (int s = 0; s < 4; ++s) {                                           \
        load_lds16(gA + (size_t)(T) * 64 + s * 16, &ldsA[P][s * 4096 + w * 512]); \
        load_lds16(gB + (size_t)(T) * 64 + s * 16, &ldsB[P][s * 4096 + w * 512]); \
      }                                                                       \
    } while (0)

  #define KTILE_COMPUTE(P)                                                    \
    do {                                                                      \
      const bf16x8* Af = (const bf16x8*)&ldsA[P][0];                          \
      const bf16x8* Bf = (const bf16x8*)&ldsB[P][0];                          \
      _Pragma("unroll")                                                       \
      for (int ks = 0; ks < 2; ++ks) {                                        \
        bf16x8 a[8], b[4];                                                    \
        _Pragma("unroll")                                                     \
        for (int m = 0; m < 8; m++) a[m] = Af[ks * 1024 + kofA + m * 16];     \
        _Pragma("unroll")                                                     \
        for (int n = 0; n < 4; n++) b[n] = Bf[ks * 1024 + kofB + n * 16];     \
        __builtin_amdgcn_s_setprio(1);                                        \
        _Pragma("unroll")                                                     \
        for (int m = 0; m < 8; m++)                                           \
          _Pragma("unroll")                                                   \
          for (int n = 0; n < 4; n++)                                         \
            acc[m][n] = __builtin_amdgcn_mfma_f32_16x16x32_bf16(a[m], b[n],   \
                                                                acc[m][n], 0, 0, 0); \
        __builtin_amdgcn_s_setprio(0);                                        \
      }                                                                       \
    } while (0)

  // prologue: stage tile 0 into buffer 0
  STAGE(0, 0);

  int p = 0;
  for (int t = 0; t + 1 < NTILES; ++t) {
    STAGE(t + 1, p ^ 1);                      // 8 loads in flight across compute
    asm volatile("s_waitcnt vmcnt(8)" ::: "memory");  // tile t landed; t+1 in flight
    __builtin_amdgcn_sched_barrier(0);
    __builtin_amdgcn_s_barrier();             // tile t globally complete
    __builtin_amdgcn_sched_barrier(0);
    KTILE_COMPUTE(p);
    __builtin_amdgcn_sched_barrier(0);
    __builtin_amdgcn_s_barrier();             // all reads of buf p done (next STAGE overwrites)
    p ^= 1;
  }
  // last tile: drain
  asm volatile("s_waitcnt vmcnt(0)" ::: "memory");
  __builtin_amdgcn_sched_barrier(0);
  __builtin_amdgcn_s_barrier();
  __builtin_amdgcn_sched_barrier(0);
  KTILE_COMPUTE(p);

  // ---- fused masked reduction ----
  // acc[m][n][r] = G[bi*256 + wr*128 + m*16 + (lane>>4)*4 + r]
  //                 [bj*256 + nc*64  + n*16 + (lane&15)]
  int tcol[4];
  #pragma unroll
  for (int n = 0; n < 4; n++) tcol[n] = tgt[bj * BM + nc * 64 + n * 16 + (lane & 15)];
  int rbase = bi * BM + wr * 128 + (lane >> 4) * 4;

  #pragma unroll
  for (int m = 0; m < 8; m++) {
    #pragma unroll
    for (int r = 0; r < 4; r++) {
      int grow = rbase + m * 16 + r;
      int trow = tgt[grow];
      float ap = -__builtin_inff(), an = __builtin_inff();
      #pragma unroll
      for (int n = 0; n < 4; n++) {
        float d = -acc[m][n][r];
        bool same = (trow == tcol[n]);
        ap = same ? fmaxf(ap, d) : ap;
        an = same ? an : fminf(an, d);
      }
      #pragma unroll
      for (int s = 1; s < 16; s <<= 1) {
        ap = fmaxf(ap, __shfl_xor(ap, s));
        an = fminf(an, __shfl_xor(an, s));
      }
      if ((lane & 15) == 0) {
        atomicMaxF(&dap[grow], ap);
        atomicMinF(&dan[grow], an);
      }
    }
  }
  #undef STAGE
  #undef KTILE_COMPUTE
}

// ---------------- final loss ----------------
__global__ __launch_bounds__(256) void loss_kernel(const float* __restrict__ dap,
                                                   const float* __restrict__ dan,
                                                   float* __restrict__ out) {
  int t = threadIdx.x;
  float s = 0.f;
  for (int i = t; i < NROWS; i += 256) {
    float v = dap[i] - dan[i] + MARGIN_F;
    s += v > 0.f ? v : 0.f;
  }
  #pragma unroll
  for (int sh = 1; sh < 64; sh <<= 1) s += __shfl_xor(s, sh);
  __shared__ float ws[4];
  if ((t & 63) == 0) ws[t >> 6] = s;
  __syncthreads();
  if (t == 0) out[0] = (ws[0] + ws[1] + ws[2] + ws[3]) * (1.0f / (float)NROWS);
}

extern "C" void kernel_launch(void* const* d_in, const int* in_sizes, int n_in,
                              void* d_out, int out_size, void* d_ws, size_t ws_size,
                              hipStream_t stream) {
  const float* inputs = (const float*)d_in[0];
  const int* targets = (const int*)d_in[1];
  short* l2 = (short*)d_ws;
  float* dap = (float*)((char*)d_ws + (size_t)NROWS * DIMS * 2);
  float* dan = dap + NROWS;
  float* out = (float*)d_out;

  hipLaunchKernelGGL(norm_kernel, dim3(NROWS), dim3(256), 0, stream,
                     inputs, l2, dap, dan);
  hipLaunchKernelGGL(gemm_reduce_kernel, dim3(NTB * NTB), dim3(512), 0, stream,
                     l2, targets, dap, dan);
  hipLaunchKernelGGL(loss_kernel, dim3(1), dim3(256), 0, stream, dap, dan, out);
}

// Round 4
// 108.095 us; speedup vs baseline: 1.6808x; 1.6808x over previous
//
#include <hip/hip_runtime.h>
#include <hip/hip_bf16.h>
#include <stdint.h>

#define NROWS 4096
#define DIMS  2048
#define BM    256
#define BK    64
#define NTILES (DIMS / BK)   // 32
#define NTB   (NROWS / BM)   // 16 -> 256 blocks
#define MARGIN_F 0.3f

typedef __attribute__((ext_vector_type(8))) short bf16x8;
typedef __attribute__((ext_vector_type(4))) float f32x4;
typedef __attribute__((ext_vector_type(4))) unsigned short us4;

__device__ inline unsigned short f2bf(float x) {
  union { float f; unsigned int u; } c; c.f = x;
  unsigned int lsb = (c.u >> 16) & 1u;
  c.u += 0x7fffu + lsb;               // round-to-nearest-even
  return (unsigned short)(c.u >> 16);
}

__device__ inline void atomicMaxF(float* addr, float v) {
  if (v >= 0.f) atomicMax((int*)addr, __float_as_int(v));
  else          atomicMin((unsigned int*)addr, __float_as_uint(v));
}
__device__ inline void atomicMinF(float* addr, float v) {
  if (v >= 0.f) atomicMin((int*)addr, __float_as_int(v));
  else          atomicMax((unsigned int*)addr, __float_as_uint(v));
}

__device__ inline void load_lds16(const void* g, void* l) {
  __builtin_amdgcn_global_load_lds(
      (const __attribute__((address_space(1))) void*)(g),
      (__attribute__((address_space(3))) void*)(l), 16, 0, 0);
}

// ---------------- normalize rows to bf16 + init dap/dan ----------------
__global__ __launch_bounds__(256) void norm_kernel(const float* __restrict__ in,
                                                   short* __restrict__ l2,
                                                   float* __restrict__ dap,
                                                   float* __restrict__ dan) {
  int row = blockIdx.x;
  int t = threadIdx.x;
  const float4* rin = (const float4*)(in + (size_t)row * DIMS);
  float4 v0 = rin[t];
  float4 v1 = rin[t + 256];
  float ss = v0.x*v0.x + v0.y*v0.y + v0.z*v0.z + v0.w*v0.w
           + v1.x*v1.x + v1.y*v1.y + v1.z*v1.z + v1.w*v1.w;
  #pragma unroll
  for (int s = 1; s < 64; s <<= 1) ss += __shfl_xor(ss, s);
  __shared__ float wsum[4];
  if ((t & 63) == 0) wsum[t >> 6] = ss;
  __syncthreads();
  float tot = wsum[0] + wsum[1] + wsum[2] + wsum[3];
  float rn = 1.0f / sqrtf(tot);
  short* orow = l2 + (size_t)row * DIMS;
  us4 o0, o1;
  o0.x = f2bf(v0.x * rn); o0.y = f2bf(v0.y * rn);
  o0.z = f2bf(v0.z * rn); o0.w = f2bf(v0.w * rn);
  o1.x = f2bf(v1.x * rn); o1.y = f2bf(v1.y * rn);
  o1.z = f2bf(v1.z * rn); o1.w = f2bf(v1.w * rn);
  *(us4*)(orow + 4 * t) = o0;
  *(us4*)(orow + 4 * t + 1024) = o1;
  if (t == 0) { dap[row] = -__builtin_inff(); dan[row] = __builtin_inff(); }
}

// ---------------- fused GEMM (G = L . L^T) + masked row max/min ----------------
// 256x256 tile, 8 waves (2M x 4N, each owns 128x64), BK=64, double-buffered
// 128 KB LDS, 16x16x32 bf16 MFMA, 2 phases per K-tile.
// LDS tile layout: row-major [256 rows][8 chunks of 16B], with XOR swizzle
// slot = chunk ^ (row & 7). Staging writes LINEAR slots (global_load_lds
// constraint) from a pre-swizzled COALESCED global source (each wave reads
// 8 rows x 128B contiguous); fragment ds_read_b128 applies the same XOR ->
// conflict-free (2-way max per 16-lane quarter).
__global__ __launch_bounds__(512, 2) void gemm_reduce_kernel(
    const short* __restrict__ l2, const int* __restrict__ tgt,
    float* __restrict__ dap, float* __restrict__ dan) {
  __shared__ __attribute__((aligned(16))) short ldsA[2][16384];  // 2 x 32 KB
  __shared__ __attribute__((aligned(16))) short ldsB[2][16384];  // 2 x 32 KB

  // XCD-chunked bijective swizzle (256 blocks, 8 XCDs -> 32 contiguous per XCD)
  int c = blockIdx.x;
  int swz = (c & 7) * 32 + (c >> 3);
  int bi = swz >> 4, bj = swz & 15;

  int tid = threadIdx.x;
  int lane = tid & 63, w = tid >> 6;
  int wr = w >> 2;        // 0..1  (M half: 128 rows)
  int nc = w & 3;         // 0..3  (N quarter: 64 cols)

  f32x4 acc[8][4];
  #pragma unroll
  for (int m = 0; m < 8; m++)
    #pragma unroll
    for (int n = 0; n < 4; n++) acc[m][n] = (f32x4){0.f, 0.f, 0.f, 0.f};

  // --- staging source (coalesced, pre-swizzled chunk within each row) ---
  // thread tid handles LDS linear slot si = j*512 + tid (j=0..3):
  //   row = j*64 + (tid>>3), slot-chunk = tid&7, data-chunk = (tid&7)^(row&7)
  int r8 = tid >> 3;                      // 0..63
  int csw = (tid & 7) ^ (r8 & 7);         // row&7 == r8&7 for all j (64%8==0)
  const short* gA = l2 + ((size_t)bi * BM + r8) * DIMS + csw * 8;
  const short* gB = l2 + ((size_t)bj * BM + r8) * DIMS + csw * 8;

  // --- fragment read indices (shorts), swizzled ---
  int laneq = lane & 15, g = lane >> 4;
  int fsw = (g ^ (lane & 7)) * 8;         // ks=0 chunk offset; ks=1 = XOR 32
  int idxA0 = (wr * 128 + laneq) * 64 + fsw;
  int idxB0 = (nc * 64 + laneq) * 64 + fsw;

  #define STAGE_A(T, P)                                                       \
    do {                                                                      \
      _Pragma("unroll")                                                       \
      for (int j = 0; j < 4; ++j)                                             \
        load_lds16(gA + (size_t)(j * 64) * DIMS + (size_t)(T) * BK,           \
                   &ldsA[P][j * 4096 + w * 512]);                             \
    } while (0)
  #define STAGE_B(T, P)                                                       \
    do {                                                                      \
      _Pragma("unroll")                                                       \
      for (int j = 0; j < 4; ++j)                                             \
        load_lds16(gB + (size_t)(j * 64) * DIMS + (size_t)(T) * BK,           \
                   &ldsB[P][j * 4096 + w * 512]);                             \
    } while (0)

  #define PHASE_CORE(P, KSX)                                                  \
    do {                                                                      \
      bf16x8 a[8], b[4];                                                      \
      const short* As = &ldsA[P][idxA0 ^ (KSX)];                              \
      const short* Bs = &ldsB[P][idxB0 ^ (KSX)];                              \
      _Pragma("unroll")                                                       \
      for (int m = 0; m < 8; m++) a[m] = *(const bf16x8*)(As + m * 1024);     \
      _Pragma("unroll")                                                       \
      for (int n = 0; n < 4; n++) b[n] = *(const bf16x8*)(Bs + n * 1024);     \
      __builtin_amdgcn_s_barrier();                                           \
      asm volatile("s_waitcnt lgkmcnt(0)" ::: "memory");                      \
      __builtin_amdgcn_sched_barrier(0);                                      \
      __builtin_amdgcn_s_setprio(1);                                          \
      _Pragma("unroll")                                                       \
      for (int m = 0; m < 8; m++)                                             \
        _Pragma("unroll")                                                     \
        for (int n = 0; n < 4; n++)                                           \
          acc[m][n] = __builtin_amdgcn_mfma_f32_16x16x32_bf16(a[m], b[n],     \
                                                              acc[m][n], 0, 0, 0); \
      __builtin_amdgcn_s_setprio(0);                                          \
      __builtin_amdgcn_sched_barrier(0);                                      \
    } while (0)

  // prologue: stage tile 0 into buffer 0, cold drain
  STAGE_A(0, 0);
  STAGE_B(0, 0);
  asm volatile("s_waitcnt vmcnt(0)" ::: "memory");
  __builtin_amdgcn_s_barrier();

  int p = 0;
  for (int t = 0; t < NTILES - 1; ++t) {
    // phase 0 (k 0..31): stage A(t+1), compute ks=0 of tile t
    STAGE_A(t + 1, p ^ 1);
    PHASE_CORE(p, 0);
    __builtin_amdgcn_s_barrier();
    // phase 1 (k 32..63): stage B(t+1), compute ks=1 of tile t
    STAGE_B(t + 1, p ^ 1);
    PHASE_CORE(p, 32);
    // t+1's 8 loads were issued >=1 phase ago -> near-free drain here
    asm volatile("s_waitcnt vmcnt(0)" ::: "memory");
    __builtin_amdgcn_s_barrier();
    p ^= 1;
  }
  // final tile: no staging
  PHASE_CORE(p, 0);
  __builtin_amdgcn_s_barrier();
  PHASE_CORE(p, 32);

  // ---- fused masked reduction ----
  // acc[m][n][r] = G[bi*256 + wr*128 + m*16 + (lane>>4)*4 + r]
  //                 [bj*256 + nc*64  + n*16 + (lane&15)]
  int tcol[4];
  #pragma unroll
  for (int n = 0; n < 4; n++) tcol[n] = tgt[bj * BM + nc * 64 + n * 16 + (lane & 15)];
  int rbase = bi * BM + wr * 128 + (lane >> 4) * 4;

  #pragma unroll
  for (int m = 0; m < 8; m++) {
    #pragma unroll
    for (int r = 0; r < 4; r++) {
      int grow = rbase + m * 16 + r;
      int trow = tgt[grow];
      float ap = -__builtin_inff(), an = __builtin_inff();
      #pragma unroll
      for (int n = 0; n < 4; n++) {
        float d = -acc[m][n][r];
        bool same = (trow == tcol[n]);
        ap = same ? fmaxf(ap, d) : ap;
        an = same ? an : fminf(an, d);
      }
      #pragma unroll
      for (int s = 1; s < 16; s <<= 1) {
        ap = fmaxf(ap, __shfl_xor(ap, s));
        an = fminf(an, __shfl_xor(an, s));
      }
      if ((lane & 15) == 0) {
        atomicMaxF(&dap[grow], ap);
        atomicMinF(&dan[grow], an);
      }
    }
  }
  #undef STAGE_A
  #undef STAGE_B
  #undef PHASE_CORE
}

// ---------------- final loss ----------------
__global__ __launch_bounds__(256) void loss_kernel(const float* __restrict__ dap,
                                                   const float* __restrict__ dan,
                                                   float* __restrict__ out) {
  int t = threadIdx.x;
  float s = 0.f;
  for (int i = t; i < NROWS; i += 256) {
    float v = dap[i] - dan[i] + MARGIN_F;
    s += v > 0.f ? v : 0.f;
  }
  #pragma unroll
  for (int sh = 1; sh < 64; sh <<= 1) s += __shfl_xor(s, sh);
  __shared__ float ws[4];
  if ((t & 63) == 0) ws[t >> 6] = s;
  __syncthreads();
  if (t == 0) out[0] = (ws[0] + ws[1] + ws[2] + ws[3]) * (1.0f / (float)NROWS);
}

extern "C" void kernel_launch(void* const* d_in, const int* in_sizes, int n_in,
                              void* d_out, int out_size, void* d_ws, size_t ws_size,
                              hipStream_t stream) {
  const float* inputs = (const float*)d_in[0];
  const int* targets = (const int*)d_in[1];
  short* l2 = (short*)d_ws;
  float* dap = (float*)((char*)d_ws + (size_t)NROWS * DIMS * 2);
  float* dan = dap + NROWS;
  float* out = (float*)d_out;

  hipLaunchKernelGGL(norm_kernel, dim3(NROWS), dim3(256), 0, stream,
                     inputs, l2, dap, dan);
  hipLaunchKernelGGL(gemm_reduce_kernel, dim3(NTB * NTB), dim3(512), 0, stream,
                     l2, targets, dap, dan);
  hipLaunchKernelGGL(loss_kernel, dim3(1), dim3(256), 0, stream, dap, dan, out);
}

// Round 5
// 101.545 us; speedup vs baseline: 1.7892x; 1.0645x over previous
//
#include <hip/hip_runtime.h>
#include <hip/hip_bf16.h>
#include <stdint.h>

#define NROWS 4096
#define DIMS  2048
#define BM    256
#define BK    64
#define NTILES (DIMS / BK)   // 32
#define NTB   (NROWS / BM)   // 16 -> 256 blocks
#define MARGIN_F 0.3f

typedef __attribute__((ext_vector_type(8))) short bf16x8;
typedef __attribute__((ext_vector_type(4))) float f32x4;
typedef __attribute__((ext_vector_type(4))) unsigned short us4;

__device__ inline unsigned short f2bf(float x) {
  union { float f; unsigned int u; } c; c.f = x;
  unsigned int lsb = (c.u >> 16) & 1u;
  c.u += 0x7fffu + lsb;               // round-to-nearest-even
  return (unsigned short)(c.u >> 16);
}

__device__ inline void atomicMaxF(float* addr, float v) {
  if (v >= 0.f) atomicMax((int*)addr, __float_as_int(v));
  else          atomicMin((unsigned int*)addr, __float_as_uint(v));
}
__device__ inline void atomicMinF(float* addr, float v) {
  if (v >= 0.f) atomicMin((int*)addr, __float_as_int(v));
  else          atomicMax((unsigned int*)addr, __float_as_uint(v));
}

__device__ inline void load_lds16(const void* g, void* l) {
  __builtin_amdgcn_global_load_lds(
      (const __attribute__((address_space(1))) void*)(g),
      (__attribute__((address_space(3))) void*)(l), 16, 0, 0);
}

// ---------------- normalize rows to bf16 + init dap/dan ----------------
__global__ __launch_bounds__(256) void norm_kernel(const float* __restrict__ in,
                                                   short* __restrict__ l2,
                                                   float* __restrict__ dap,
                                                   float* __restrict__ dan) {
  int row = blockIdx.x;
  int t = threadIdx.x;
  const float4* rin = (const float4*)(in + (size_t)row * DIMS);
  float4 v0 = rin[t];
  float4 v1 = rin[t + 256];
  float ss = v0.x*v0.x + v0.y*v0.y + v0.z*v0.z + v0.w*v0.w
           + v1.x*v1.x + v1.y*v1.y + v1.z*v1.z + v1.w*v1.w;
  #pragma unroll
  for (int s = 1; s < 64; s <<= 1) ss += __shfl_xor(ss, s);
  __shared__ float wsum[4];
  if ((t & 63) == 0) wsum[t >> 6] = ss;
  __syncthreads();
  float tot = wsum[0] + wsum[1] + wsum[2] + wsum[3];
  float rn = 1.0f / sqrtf(tot);
  short* orow = l2 + (size_t)row * DIMS;
  us4 o0, o1;
  o0.x = f2bf(v0.x * rn); o0.y = f2bf(v0.y * rn);
  o0.z = f2bf(v0.z * rn); o0.w = f2bf(v0.w * rn);
  o1.x = f2bf(v1.x * rn); o1.y = f2bf(v1.y * rn);
  o1.z = f2bf(v1.z * rn); o1.w = f2bf(v1.w * rn);
  *(us4*)(orow + 4 * t) = o0;
  *(us4*)(orow + 4 * t + 1024) = o1;
  if (t == 0) { dap[row] = -__builtin_inff(); dan[row] = __builtin_inff(); }
}

// ---------------- fused GEMM (G = L . L^T) + masked row max/min ----------------
// 256x256 tile, 8 waves (2M x 4N, wave tile 128x64), BK=64, 16x16x32 bf16 MFMA.
// 4 phases per K-tile keyed by (m-half, ks-half), 16 MFMA each.
// LDS per set per operand: [2 ks][256 rows][32 k] bf16 (ks-major halves, 16 KB),
// chunk-swizzled: LDS chunk-slot c (16B) of a row holds data chunk q = c^((row>>1)&3).
// Staging: 1 half-tile per phase (2 global_load_lds x 16B/thread, coalesced 64B
// segments, linear LDS dest + pre-swizzled global source). Counted vmcnt(6)
// gates at Ph0/Ph2 wait loads issued 3-4 phases earlier (never drain to 0).
__global__ __launch_bounds__(512, 2) void gemm_reduce_kernel(
    const short* __restrict__ l2, const int* __restrict__ tgt,
    float* __restrict__ dap, float* __restrict__ dan) {
  __shared__ __attribute__((aligned(16))) short ldsA[2][16384];  // 2 sets x 32 KB
  __shared__ __attribute__((aligned(16))) short ldsB[2][16384];

  // XCD-chunked bijective swizzle (256 blocks, 8 XCDs -> 32 contiguous per XCD)
  int c = blockIdx.x;
  int swz = (c & 7) * 32 + (c >> 3);
  int bi = swz >> 4, bj = swz & 15;

  int tid = threadIdx.x;
  int lane = tid & 63, w = tid >> 6;
  int wr = w >> 2;        // 0..1  (M half: 128 rows)
  int nc = w & 3;         // 0..3  (N quarter: 64 cols)

  f32x4 acc[8][4];
  #pragma unroll
  for (int m = 0; m < 8; m++)
    #pragma unroll
    for (int n = 0; n < 4; n++) acc[m][n] = (f32x4){0.f, 0.f, 0.f, 0.f};

  // --- staging source: thread tid covers LDS slots tid and tid+512 of a half ---
  // slot s: row = s>>2, slot-chunk = s&3, data-chunk q = (s&3) ^ ((row>>1)&3).
  // Both slots share the same q (rows differ by 128).
  int srow = tid >> 2;                               // 0..127
  int qq = (tid & 3) ^ ((tid >> 3) & 3);
  const short* gA = l2 + ((size_t)(bi * BM + srow)) * DIMS + qq * 8;
  const short* gB = l2 + ((size_t)(bj * BM + srow)) * DIMS + qq * 8;

  // --- fragment read offsets (shorts, within a ks-half) ---
  int laneq = lane & 15, g = lane >> 4;
  int fc = (g ^ ((laneq >> 1) & 3)) * 8;             // swizzled chunk slot
  int aOff = (wr * 128 + laneq) * 32 + fc;
  int bOff = (nc * 64 + laneq) * 32 + fc;

  #define STAGE_A(T, KS, P)                                                   \
    do {                                                                      \
      load_lds16(gA + (size_t)(T) * 64 + (KS) * 32,                           \
                 &ldsA[P][(KS) * 8192 + w * 512]);                            \
      load_lds16(gA + 128 * (size_t)DIMS + (size_t)(T) * 64 + (KS) * 32,      \
                 &ldsA[P][(KS) * 8192 + 4096 + w * 512]);                     \
    } while (0)
  #define STAGE_B(T, KS, P)                                                   \
    do {                                                                      \
      load_lds16(gB + (size_t)(T) * 64 + (KS) * 32,                           \
                 &ldsB[P][(KS) * 8192 + w * 512]);                            \
      load_lds16(gB + 128 * (size_t)DIMS + (size_t)(T) * 64 + (KS) * 32,      \
                 &ldsB[P][(KS) * 8192 + 4096 + w * 512]);                     \
    } while (0)

  #define READ_A(MO, KS, P)                                                   \
    _Pragma("unroll")                                                         \
    for (int m = 0; m < 4; m++)                                               \
      a[m] = *(const bf16x8*)&ldsA[P][(KS) * 8192 + aOff + ((MO) + m) * 512];
  #define READ_B(KS, P)                                                       \
    _Pragma("unroll")                                                         \
    for (int n = 0; n < 4; n++)                                               \
      b[n] = *(const bf16x8*)&ldsB[P][(KS) * 8192 + bOff + n * 512];

  #define MFMA16(MO)                                                          \
    __builtin_amdgcn_s_setprio(1);                                            \
    _Pragma("unroll")                                                         \
    for (int m = 0; m < 4; m++)                                               \
      _Pragma("unroll")                                                       \
      for (int n = 0; n < 4; n++)                                             \
        acc[(MO) + m][n] = __builtin_amdgcn_mfma_f32_16x16x32_bf16(           \
            a[m], b[n], acc[(MO) + m][n], 0, 0, 0);                           \
    __builtin_amdgcn_s_setprio(0);                                            \
    __builtin_amdgcn_sched_barrier(0);

  #define LGKM0                                                               \
    asm volatile("s_waitcnt lgkmcnt(0)" ::: "memory");                        \
    __builtin_amdgcn_sched_barrier(0);
  #define GATE6                                                               \
    asm volatile("s_waitcnt vmcnt(6)" ::: "memory");                          \
    __builtin_amdgcn_s_barrier();                                             \
    __builtin_amdgcn_sched_barrier(0);
  #define BAR                                                                 \
    __builtin_amdgcn_s_barrier();

  #define ITER(P, TN)                                                         \
    do {                                                                      \
      bf16x8 a[4], b[4];                                                      \
      /* Ph0: gate ks0, compute (m0-3, ks0) */                                \
      STAGE_A(TN, 0, (P) ^ 1);                                                \
      GATE6                                                                   \
      READ_B(0, P)                                                            \
      READ_A(0, 0, P)                                                         \
      LGKM0                                                                   \
      MFMA16(0)                                                               \
      BAR                                                                     \
      /* Ph1: compute (m4-7, ks0), B held in regs */                          \
      STAGE_B(TN, 0, (P) ^ 1);                                                \
      READ_A(4, 0, P)                                                         \
      LGKM0                                                                   \
      MFMA16(4)                                                               \
      BAR                                                                     \
      /* Ph2: gate ks1, compute (m0-3, ks1) */                                \
      STAGE_A(TN, 1, (P) ^ 1);                                                \
      GATE6                                                                   \
      READ_B(1, P)                                                            \
      READ_A(0, 1, P)                                                         \
      LGKM0                                                                   \
      MFMA16(0)                                                               \
      BAR                                                                     \
      /* Ph3: compute (m4-7, ks1) */                                          \
      STAGE_B(TN, 1, (P) ^ 1);                                                \
      READ_A(4, 1, P)                                                         \
      LGKM0                                                                   \
      MFMA16(4)                                                               \
      BAR                                                                     \
    } while (0)

  // prologue: stage tile 0's 4 halves into set 0 (same issue order as loop)
  STAGE_A(0, 0, 0);
  STAGE_B(0, 0, 0);
  STAGE_A(0, 1, 0);
  STAGE_B(0, 1, 0);

  #pragma unroll 1
  for (int kt = 0; kt < NTILES; kt += 2) {
    int tnA = kt + 1;                                   // always < NTILES
    int tnB = (kt + 2 < NTILES) ? kt + 2 : NTILES - 1;  // last: harmless re-stage
    ITER(0, tnA);
    ITER(1, tnB);
  }

  // ---- fused masked reduction ----
  // acc[m][n][r] = G[bi*256 + wr*128 + m*16 + (lane>>4)*4 + r]
  //                 [bj*256 + nc*64  + n*16 + (lane&15)]
  int tcol[4];
  #pragma unroll
  for (int n = 0; n < 4; n++) tcol[n] = tgt[bj * BM + nc * 64 + n * 16 + (lane & 15)];
  int rbase = bi * BM + wr * 128 + (lane >> 4) * 4;

  #pragma unroll
  for (int m = 0; m < 8; m++) {
    #pragma unroll
    for (int r = 0; r < 4; r++) {
      int grow = rbase + m * 16 + r;
      int trow = tgt[grow];
      float ap = -__builtin_inff(), an = __builtin_inff();
      #pragma unroll
      for (int n = 0; n < 4; n++) {
        float d = -acc[m][n][r];
        bool same = (trow == tcol[n]);
        ap = same ? fmaxf(ap, d) : ap;
        an = same ? an : fminf(an, d);
      }
      #pragma unroll
      for (int s = 1; s < 16; s <<= 1) {
        ap = fmaxf(ap, __shfl_xor(ap, s));
        an = fminf(an, __shfl_xor(an, s));
      }
      if ((lane & 15) == 0) {
        atomicMaxF(&dap[grow], ap);
        atomicMinF(&dan[grow], an);
      }
    }
  }
  #undef STAGE_A
  #undef STAGE_B
  #undef READ_A
  #undef READ_B
  #undef MFMA16
  #undef LGKM0
  #undef GATE6
  #undef BAR
  #undef ITER
}

// ---------------- final loss ----------------
__global__ __launch_bounds__(256) void loss_kernel(const float* __restrict__ dap,
                                                   const float* __restrict__ dan,
                                                   float* __restrict__ out) {
  int t = threadIdx.x;
  float s = 0.f;
  for (int i = t; i < NROWS; i += 256) {
    float v = dap[i] - dan[i] + MARGIN_F;
    s += v > 0.f ? v : 0.f;
  }
  #pragma unroll
  for (int sh = 1; sh < 64; sh <<= 1) s += __shfl_xor(s, sh);
  __shared__ float ws[4];
  if ((t & 63) == 0) ws[t >> 6] = s;
  __syncthreads();
  if (t == 0) out[0] = (ws[0] + ws[1] + ws[2] + ws[3]) * (1.0f / (float)NROWS);
}

extern "C" void kernel_launch(void* const* d_in, const int* in_sizes, int n_in,
                              void* d_out, int out_size, void* d_ws, size_t ws_size,
                              hipStream_t stream) {
  const float* inputs = (const float*)d_in[0];
  const int* targets = (const int*)d_in[1];
  short* l2 = (short*)d_ws;
  float* dap = (float*)((char*)d_ws + (size_t)NROWS * DIMS * 2);
  float* dan = dap + NROWS;
  float* out = (float*)d_out;

  hipLaunchKernelGGL(norm_kernel, dim3(NROWS), dim3(256), 0, stream,
                     inputs, l2, dap, dan);
  hipLaunchKernelGGL(gemm_reduce_kernel, dim3(NTB * NTB), dim3(512), 0, stream,
                     l2, targets, dap, dan);
  hipLaunchKernelGGL(loss_kernel, dim3(1), dim3(256), 0, stream, dap, dan, out);
}

// Round 6
// 97.722 us; speedup vs baseline: 1.8592x; 1.0391x over previous
//
#include <hip/hip_runtime.h>
#include <hip/hip_bf16.h>
#include <stdint.h>

#define NROWS 4096
#define DIMS  2048
#define BM    256
#define BK    64
#define NTILES (DIMS / BK)   // 32
#define NTB   (NROWS / BM)   // 16 -> 256 blocks
#define MARGIN_F 0.3f

typedef __attribute__((ext_vector_type(8))) short bf16x8;
typedef __attribute__((ext_vector_type(4))) float f32x4;
typedef __attribute__((ext_vector_type(4))) unsigned short us4;

__device__ inline unsigned short f2bf(float x) {
  union { float f; unsigned int u; } c; c.f = x;
  unsigned int lsb = (c.u >> 16) & 1u;
  c.u += 0x7fffu + lsb;               // round-to-nearest-even
  return (unsigned short)(c.u >> 16);
}

__device__ inline void atomicMaxF(float* addr, float v) {
  if (v >= 0.f) atomicMax((int*)addr, __float_as_int(v));
  else          atomicMin((unsigned int*)addr, __float_as_uint(v));
}
__device__ inline void atomicMinF(float* addr, float v) {
  if (v >= 0.f) atomicMin((int*)addr, __float_as_int(v));
  else          atomicMax((unsigned int*)addr, __float_as_uint(v));
}

__device__ inline void load_lds16(const void* g, void* l) {
  __builtin_amdgcn_global_load_lds(
      (const __attribute__((address_space(1))) void*)(g),
      (__attribute__((address_space(3))) void*)(l), 16, 0, 0);
}

// ---------------- normalize rows to bf16 + init dap/dan ----------------
__global__ __launch_bounds__(256) void norm_kernel(const float* __restrict__ in,
                                                   short* __restrict__ l2,
                                                   float* __restrict__ dap,
                                                   float* __restrict__ dan) {
  int row = blockIdx.x;
  int t = threadIdx.x;
  const float4* rin = (const float4*)(in + (size_t)row * DIMS);
  float4 v0 = rin[t];
  float4 v1 = rin[t + 256];
  float ss = v0.x*v0.x + v0.y*v0.y + v0.z*v0.z + v0.w*v0.w
           + v1.x*v1.x + v1.y*v1.y + v1.z*v1.z + v1.w*v1.w;
  #pragma unroll
  for (int s = 1; s < 64; s <<= 1) ss += __shfl_xor(ss, s);
  __shared__ float wsum[4];
  if ((t & 63) == 0) wsum[t >> 6] = ss;
  __syncthreads();
  float tot = wsum[0] + wsum[1] + wsum[2] + wsum[3];
  float rn = 1.0f / sqrtf(tot);
  short* orow = l2 + (size_t)row * DIMS;
  us4 o0, o1;
  o0.x = f2bf(v0.x * rn); o0.y = f2bf(v0.y * rn);
  o0.z = f2bf(v0.z * rn); o0.w = f2bf(v0.w * rn);
  o1.x = f2bf(v1.x * rn); o1.y = f2bf(v1.y * rn);
  o1.z = f2bf(v1.z * rn); o1.w = f2bf(v1.w * rn);
  *(us4*)(orow + 4 * t) = o0;
  *(us4*)(orow + 4 * t + 1024) = o1;
  if (t == 0) { dap[row] = -__builtin_inff(); dan[row] = __builtin_inff(); }
}

// ---------------- fused GEMM (G = L . L^T) + masked row max/min ----------------
// 256x256 tile, 8 waves (2M x 4N, wave tile 128x64), BK=64, 16x16x32 bf16 MFMA.
// Software-pipelined 4-phase ring per K-tile: fragment reads issued ONE PHASE
// AHEAD of their MFMA (counted lgkmcnt waits only prior-phase reads); one
// half-tile staged per phase; counted vmcnt(2) gates + barrier at P0/P2 only
// (waits loads issued 2-3 phases earlier, never a cold drain).
// LDS per set per operand: [2 ks][256 rows][32 k] bf16, chunk-swizzled
// q = c ^ ((row>>1)&3); staging linear dest + pre-swizzled coalesced source.
__global__ __launch_bounds__(512, 2) void gemm_reduce_kernel(
    const short* __restrict__ l2, const int* __restrict__ tgt,
    float* __restrict__ dap, float* __restrict__ dan) {
  __shared__ __attribute__((aligned(16))) short ldsA[2][16384];  // 2 sets x 32 KB
  __shared__ __attribute__((aligned(16))) short ldsB[2][16384];

  // XCD-chunked bijective swizzle (256 blocks, 8 XCDs -> 32 contiguous per XCD)
  int c = blockIdx.x;
  int swz = (c & 7) * 32 + (c >> 3);
  int bi = swz >> 4, bj = swz & 15;

  int tid = threadIdx.x;
  int lane = tid & 63, w = tid >> 6;
  int wr = w >> 2;        // 0..1  (M half: 128 rows)
  int nc = w & 3;         // 0..3  (N quarter: 64 cols)

  f32x4 acc[8][4];
  #pragma unroll
  for (int m = 0; m < 8; m++)
    #pragma unroll
    for (int n = 0; n < 4; n++) acc[m][n] = (f32x4){0.f, 0.f, 0.f, 0.f};

  // --- staging source (identical to r5: coalesced, pre-swizzled) ---
  int srow = tid >> 2;                               // 0..127
  int qq = (tid & 3) ^ ((tid >> 3) & 3);
  const short* gA = l2 + ((size_t)(bi * BM + srow)) * DIMS + qq * 8;
  const short* gB = l2 + ((size_t)(bj * BM + srow)) * DIMS + qq * 8;

  // --- fragment read offsets (identical to r5) ---
  int laneq = lane & 15, g = lane >> 4;
  int fc = (g ^ ((laneq >> 1) & 3)) * 8;             // swizzled chunk slot
  int aOff = (wr * 128 + laneq) * 32 + fc;
  int bOff = (nc * 64 + laneq) * 32 + fc;

  bf16x8 aX[4], aY[4], bX[4], bY[4];

  #define STAGE_A(T, KS, P)                                                   \
    do {                                                                      \
      load_lds16(gA + (size_t)(T) * 64 + (KS) * 32,                           \
                 &ldsA[P][(KS) * 8192 + w * 512]);                            \
      load_lds16(gA + 128 * (size_t)DIMS + (size_t)(T) * 64 + (KS) * 32,      \
                 &ldsA[P][(KS) * 8192 + 4096 + w * 512]);                     \
    } while (0)
  #define STAGE_B(T, KS, P)                                                   \
    do {                                                                      \
      load_lds16(gB + (size_t)(T) * 64 + (KS) * 32,                           \
                 &ldsB[P][(KS) * 8192 + w * 512]);                            \
      load_lds16(gB + 128 * (size_t)DIMS + (size_t)(T) * 64 + (KS) * 32,      \
                 &ldsB[P][(KS) * 8192 + 4096 + w * 512]);                     \
    } while (0)

  #define READ_A(DST, MO, KS, P)                                              \
    _Pragma("unroll")                                                         \
    for (int m = 0; m < 4; m++)                                               \
      DST[m] = *(const bf16x8*)&ldsA[P][(KS) * 8192 + aOff + ((MO) + m) * 512];
  #define READ_B(DST, KS, P)                                                  \
    _Pragma("unroll")                                                         \
    for (int n = 0; n < 4; n++)                                               \
      DST[n] = *(const bf16x8*)&ldsB[P][(KS) * 8192 + bOff + n * 512];

  #define MFMA16(MO, AR, BR)                                                  \
    __builtin_amdgcn_s_setprio(1);                                            \
    _Pragma("unroll")                                                         \
    for (int m = 0; m < 4; m++)                                               \
      _Pragma("unroll")                                                       \
      for (int n = 0; n < 4; n++)                                             \
        acc[(MO) + m][n] = __builtin_amdgcn_mfma_f32_16x16x32_bf16(           \
            AR[m], BR[n], acc[(MO) + m][n], 0, 0, 0);                         \
    __builtin_amdgcn_s_setprio(0);                                            \
    __builtin_amdgcn_sched_barrier(0);

  #define LGKM(N)                                                             \
    asm volatile("s_waitcnt lgkmcnt(" #N ")" ::: "memory");                   \
    __builtin_amdgcn_sched_barrier(0);
  #define VM(N)                                                               \
    asm volatile("s_waitcnt vmcnt(" #N ")" ::: "memory");
  #define BAR __builtin_amdgcn_s_barrier();

  // Ring: P0 consumes (aX,bX) [read at prev P3], P1 (aY,bX) [P0],
  //       P2 (aX,bY) [P1], P3 (aY,bY) [P2]; P3 reads next tile's ks0.
  #define ITER(P, TN)                                                         \
    do {                                                                      \
      /* P0: gate publishes (ks1 of tile t); compute (m0-3, ks0) */           \
      READ_A(aY, 4, 0, P)                                                     \
      STAGE_A(TN, 0, (P) ^ 1);                                                \
      VM(2)                                                                   \
      BAR                                                                     \
      LGKM(4)                                                                 \
      MFMA16(0, aX, bX)                                                       \
      /* P1: compute (m4-7, ks0) */                                           \
      READ_B(bY, 1, P)                                                        \
      READ_A(aX, 0, 1, P)                                                     \
      STAGE_B(TN, 0, (P) ^ 1);                                                \
      LGKM(8)                                                                 \
      MFMA16(4, aY, bX)                                                       \
      /* P2: gate publishes (ks0 of tile t+1); compute (m0-3, ks1) */         \
      READ_A(aY, 4, 1, P)                                                     \
      STAGE_A(TN, 1, (P) ^ 1);                                                \
      VM(2)                                                                   \
      BAR                                                                     \
      LGKM(4)                                                                 \
      MFMA16(0, aX, bY)                                                       \
      /* P3: read next tile's ks0 from other set; compute (m4-7, ks1) */      \
      READ_B(bX, 0, (P) ^ 1)                                                  \
      READ_A(aX, 0, 0, (P) ^ 1)                                               \
      STAGE_B(TN, 1, (P) ^ 1);                                                \
      LGKM(8)                                                                 \
      MFMA16(4, aY, bY)                                                       \
    } while (0)

  // prologue: stage tile 0 (4 half-stages, 8 vm units) into set 0
  STAGE_A(0, 0, 0);
  STAGE_B(0, 0, 0);
  STAGE_A(0, 1, 0);
  STAGE_B(0, 1, 0);
  VM(4)            // drain A(0,ks0), B(0,ks0); ks1 halves stay in flight
  BAR
  READ_B(bX, 0, 0)
  READ_A(aX, 0, 0, 0)

  #pragma unroll 1
  for (int kt = 0; kt < 30; kt += 2) {
    ITER(0, kt + 1);
    ITER(1, kt + 2);
  }
  ITER(0, 31);     // t=30: stages tile 31 into set 1

  // ---- tail: tile 31 in set 1, no staging ----
  /* P0 */
  READ_A(aY, 4, 0, 1)
  VM(0)            // drain A(31,ks1), B(31,ks1) (issued 2-3 phases ago)
  BAR
  LGKM(4)
  MFMA16(0, aX, bX)
  /* P1 */
  READ_B(bY, 1, 1)
  READ_A(aX, 0, 1, 1)
  LGKM(8)
  MFMA16(4, aY, bX)
  /* P2 */
  READ_A(aY, 4, 1, 1)
  LGKM(4)
  MFMA16(0, aX, bY)
  /* P3 */
  LGKM(0)
  MFMA16(4, aY, bY)

  // ---- fused masked reduction ----
  // acc[m][n][r] = G[bi*256 + wr*128 + m*16 + (lane>>4)*4 + r]
  //                 [bj*256 + nc*64  + n*16 + (lane&15)]
  int tcol[4];
  #pragma unroll
  for (int n = 0; n < 4; n++) tcol[n] = tgt[bj * BM + nc * 64 + n * 16 + (lane & 15)];
  int rbase = bi * BM + wr * 128 + (lane >> 4) * 4;

  #pragma unroll
  for (int m = 0; m < 8; m++) {
    #pragma unroll
    for (int r = 0; r < 4; r++) {
      int grow = rbase + m * 16 + r;
      int trow = tgt[grow];
      float ap = -__builtin_inff(), an = __builtin_inff();
      #pragma unroll
      for (int n = 0; n < 4; n++) {
        float d = -acc[m][n][r];
        bool same = (trow == tcol[n]);
        ap = same ? fmaxf(ap, d) : ap;
        an = same ? an : fminf(an, d);
      }
      #pragma unroll
      for (int s = 1; s < 16; s <<= 1) {
        ap = fmaxf(ap, __shfl_xor(ap, s));
        an = fminf(an, __shfl_xor(an, s));
      }
      if ((lane & 15) == 0) {
        atomicMaxF(&dap[grow], ap);
        atomicMinF(&dan[grow], an);
      }
    }
  }
  #undef STAGE_A
  #undef STAGE_B
  #undef READ_A
  #undef READ_B
  #undef MFMA16
  #undef LGKM
  #undef VM
  #undef BAR
  #undef ITER
}

// ---------------- final loss ----------------
__global__ __launch_bounds__(256) void loss_kernel(const float* __restrict__ dap,
                                                   const float* __restrict__ dan,
                                                   float* __restrict__ out) {
  int t = threadIdx.x;
  float s = 0.f;
  for (int i = t; i < NROWS; i += 256) {
    float v = dap[i] - dan[i] + MARGIN_F;
    s += v > 0.f ? v : 0.f;
  }
  #pragma unroll
  for (int sh = 1; sh < 64; sh <<= 1) s += __shfl_xor(s, sh);
  __shared__ float ws[4];
  if ((t & 63) == 0) ws[t >> 6] = s;
  __syncthreads();
  if (t == 0) out[0] = (ws[0] + ws[1] + ws[2] + ws[3]) * (1.0f / (float)NROWS);
}

extern "C" void kernel_launch(void* const* d_in, const int* in_sizes, int n_in,
                              void* d_out, int out_size, void* d_ws, size_t ws_size,
                              hipStream_t stream) {
  const float* inputs = (const float*)d_in[0];
  const int* targets = (const int*)d_in[1];
  short* l2 = (short*)d_ws;
  float* dap = (float*)((char*)d_ws + (size_t)NROWS * DIMS * 2);
  float* dan = dap + NROWS;
  float* out = (float*)d_out;

  hipLaunchKernelGGL(norm_kernel, dim3(NROWS), dim3(256), 0, stream,
                     inputs, l2, dap, dan);
  hipLaunchKernelGGL(gemm_reduce_kernel, dim3(NTB * NTB), dim3(512), 0, stream,
                     l2, targets, dap, dan);
  hipLaunchKernelGGL(loss_kernel, dim3(1), dim3(256), 0, stream, dap, dan, out);
}